// Round 9
// baseline (406.200 us; speedup 1.0000x reference)
//
#include <hip/hip_runtime.h>
#include <hip/hip_bf16.h>

// MDN NLL, fully fused. N=524288 Dx=128 Dt=64 M=32 K=8.
// Memory-bound target: 470 MB reads -> ~75us floor at 6.3 TB/s.
// R9 design: NO staging at all. The 16KB x-tile has 8x cross-wave reuse ->
// L1-resident (32KB/CU); x/t/y fragments load DIRECTLY from global (each
// fragment = 8 contiguous floats in the transposed scheme). Register diet:
// no staging regs, no DMA offsets, biases in LDS -> fits 128-reg cap ->
// launch_bounds(512,4) -> 2 blocks/CU. LDS ~10KB (wg + biases + ll[2]).
// ONE lgkm-only barrier/iter (ll ping-pong; re-write of buf b is separated
// from reads of b by the intervening barrier).
// R8 carried: transposed MFMA (mfma(W,x) -> sample=col=l15, m=row=lhi*4+j),
// in-lane M-reduce, in-lane gate LSE.
// R2/R5/R6 lesson: 128-cap spills IF staging overhang exists; here removed.

#define NN 524288
#define DX 128
#define DT 64
#define MDIM 32
#define KEXP 8
#define TILE_R 32
#define THREADS 512
#define GRID_MAIN 512
#define TILES_TOTAL (NN / TILE_R)        // 16384
#define TPB (TILES_TOTAL / GRID_MAIN)    // 32

typedef __bf16 bf16x8 __attribute__((ext_vector_type(8)));
typedef float f32x4 __attribute__((ext_vector_type(4)));

__device__ __forceinline__ bf16x8 cvt8(const f32x4 a, const f32x4 b) {
  bf16x8 r;
  r[0] = (__bf16)a[0]; r[1] = (__bf16)a[1]; r[2] = (__bf16)a[2]; r[3] = (__bf16)a[3];
  r[4] = (__bf16)b[0]; r[5] = (__bf16)b[1]; r[6] = (__bf16)b[2]; r[7] = (__bf16)b[3];
  return r;
}

#define MFMA16(a, b, c) __builtin_amdgcn_mfma_f32_16x16x32_bf16(a, b, c, 0, 0, 0)

// LDS-only barrier: global loads stay in flight across it (rule 18 fence).
#define B_LDS() do { \
  asm volatile("s_waitcnt lgkmcnt(0)" ::: "memory"); \
  __builtin_amdgcn_s_barrier(); \
  __builtin_amdgcn_sched_barrier(0); } while (0)

__global__ __launch_bounds__(THREADS, 4) void mdn_main(
    const float* __restrict__ x, const float* __restrict__ t,
    const float* __restrict__ y, const float* __restrict__ Wm,
    const float* __restrict__ bm, const float* __restrict__ Wv,
    const float* __restrict__ bv, const float* __restrict__ Wg,
    const float* __restrict__ bg, float* __restrict__ partials,
    float* __restrict__ out_atomic)
{
  __shared__ __align__(16) unsigned short wg_lds[2 * 64 * 8];   // 2 KB
  __shared__ __align__(16) float bm_s[KEXP * MDIM];             // 1 KB
  __shared__ __align__(16) float bv_s[KEXP * MDIM];             // 1 KB
  __shared__ __align__(16) float bg_s[KEXP];
  __shared__ float ll_s[2][TILE_R * 20];                        // 5 KB ping-pong
  __shared__ float red_s[8];

  const int tid = threadIdx.x;
  const int lane = tid & 63;
  const int wv = tid >> 6;       // wave id == expert k
  const int l15 = lane & 15;
  const int lhi = lane >> 4;     // 0..3

  // biases -> LDS (freed from registers; re-read per iter as broadcasts)
  if (tid < KEXP * MDIM) bm_s[tid] = bm[tid];
  else if (tid < 2 * KEXP * MDIM) bv_s[tid - KEXP * MDIM] = bv[tid - KEXP * MDIM];
  if (tid < KEXP) bg_s[tid] = bg[tid];

  // W fragments (A-operand of transposed MFMA): lane l15 = m-col,
  // k = lhi*8+i. ct 0,1 = Wm cols 0..15/16..31; 2,3 = Wv.
  bf16x8 bfrag[4][4];
  #pragma unroll
  for (int ct = 0; ct < 4; ++ct) {
    const float* W = (ct < 2 ? Wm : Wv) + (size_t)wv * (DX * MDIM);
    const int mcol = ((ct & 1) << 4) + l15;
    #pragma unroll
    for (int kk = 0; kk < 4; ++kk) {
      bf16x8 tmp;
      #pragma unroll
      for (int i = 0; i < 8; ++i)
        tmp[i] = (__bf16)W[(kk * 32 + lhi * 8 + i) * MDIM + mcol];
      bfrag[ct][kk] = tmp;
    }
  }
  // Gate weight fragments -> LDS (rows >= KEXP zero-padded)
  #pragma unroll
  for (int kk = 0; kk < 2; ++kk) {
    bf16x8 tmp;
    #pragma unroll
    for (int i = 0; i < 8; ++i) {
      const int d = kk * 32 + lhi * 8 + i;
      tmp[i] = (__bf16)((l15 < KEXP) ? Wg[d * KEXP + l15] : 0.f);
    }
    *(bf16x8*)((char*)wg_lds + (kk * 64 + lane) * 16) = tmp;
  }

  B_LDS();   // LDS prologue visible

  const int first = blockIdx.x * TPB;
  const int grt = wv & 1;        // gate sample-half for this wave
  float loss_acc = 0.f;
  const float HL2PI = 0.91893853320467274f;   // 0.5*log(2*pi)

  for (int it = 0; it < TPB; ++it) {
    const int cur = it & 1;
    const int row0 = (first + it) * TILE_R;

    // per-iter bias reads (LDS broadcast, 4 addresses -> conflict-free)
    const f32x4 b0 = *(const f32x4*)&bm_s[wv * MDIM + lhi * 4];
    const f32x4 b1 = *(const f32x4*)&bm_s[wv * MDIM + 16 + lhi * 4];
    const f32x4 b2 = *(const f32x4*)&bv_s[wv * MDIM + lhi * 4];
    const f32x4 b3 = *(const f32x4*)&bv_s[wv * MDIM + 16 + lhi * 4];

    // ---- transposed mean/logvar MFMAs + in-lane Gaussian-LL ----
    #pragma unroll
    for (int rt = 0; rt < 2; ++rt) {
      const int r = rt * 16 + l15;
      const float* xr = x + (size_t)(row0 + r) * DX + lhi * 8;
      f32x4 acc0 = b0, acc1 = b1, acc2 = b2, acc3 = b3;
      #pragma unroll
      for (int kk = 0; kk < 4; ++kk) {
        const f32x4 f0 = *(const f32x4*)(xr + kk * 32);
        const f32x4 f1 = *(const f32x4*)(xr + kk * 32 + 4);
        const bf16x8 xf = cvt8(f0, f1);
        acc0 = MFMA16(bfrag[0][kk], xf, acc0);
        acc1 = MFMA16(bfrag[1][kk], xf, acc1);
        acc2 = MFMA16(bfrag[2][kk], xf, acc2);
        acc3 = MFMA16(bfrag[3][kk], xf, acc3);
      }
      // D: col = l15 = sample (rt half), row = lhi*4+j = m
      const float* yr = y + (size_t)(row0 + r) * MDIM;
      const f32x4 y0v = *(const f32x4*)(yr + lhi * 4);
      const f32x4 y1v = *(const f32x4*)(yr + 16 + lhi * 4);
      float part = 0.f;
      #pragma unroll
      for (int j = 0; j < 4; ++j) {
        const float d0 = y0v[j] - acc0[j];
        const float d1 = y1v[j] - acc1[j];
        part += d0 * d0 * (0.5f * __expf(-acc2[j])) + 0.5f * acc2[j];
        part += d1 * d1 * (0.5f * __expf(-acc3[j])) + 0.5f * acc3[j];
      }
      part += __shfl_xor(part, 16);
      part += __shfl_xor(part, 32);
      if (lhi == 0) ll_s[cur][r * 20 + wv] = -(part + MDIM * HL2PI);
    }

    // ---- transposed gate MFMA (t direct from global, wg from LDS) ----
    // D[k][r]: row = lhi*4+j = expert k (lhi<2 valid), col = l15 = sample
    f32x4 lgv;
    {
      const float* tr_ = t + (size_t)(row0 + grt * 16 + l15) * DT + lhi * 8;
      f32x4 g = {0.f, 0.f, 0.f, 0.f};
      #pragma unroll
      for (int kk = 0; kk < 2; ++kk) {
        const f32x4 f0 = *(const f32x4*)(tr_ + kk * 32);
        const f32x4 f1 = *(const f32x4*)(tr_ + kk * 32 + 4);
        const bf16x8 wf = *(const bf16x8*)((const char*)wg_lds + (kk * 64 + lane) * 16);
        g = MFMA16(wf, cvt8(f0, f1), g);
      }
      const int kb = (lhi & 1) * 4;
      lgv[0] = g[0] + bg_s[kb + 0]; lgv[1] = g[1] + bg_s[kb + 1];
      lgv[2] = g[2] + bg_s[kb + 2]; lgv[3] = g[3] + bg_s[kb + 3];
    }

    B_LDS();   // the ONE barrier: ll_s[cur] visible (and prev-buf reads done)

    // ---- per-sample LSE over experts: in-lane over 4 k's + 1 shfl ----
    {
      const int r = grt * 16 + l15;
      const f32x4 lv4 = *(const f32x4*)&ll_s[cur][r * 20 + lhi * 4];  // lhi>=2: garbage, isolated
      f32x4 a4;
      a4[0] = lgv[0] + lv4[0]; a4[1] = lgv[1] + lv4[1];
      a4[2] = lgv[2] + lv4[2]; a4[3] = lgv[3] + lv4[3];
      float mg = fmaxf(fmaxf(lgv[0], lgv[1]), fmaxf(lgv[2], lgv[3]));
      float ma = fmaxf(fmaxf(a4[0], a4[1]), fmaxf(a4[2], a4[3]));
      mg = fmaxf(mg, __shfl_xor(mg, 16));
      ma = fmaxf(ma, __shfl_xor(ma, 16));
      float eg = __expf(lgv[0] - mg) + __expf(lgv[1] - mg)
               + __expf(lgv[2] - mg) + __expf(lgv[3] - mg);
      float ea = __expf(a4[0] - ma) + __expf(a4[1] - ma)
               + __expf(a4[2] - ma) + __expf(a4[3] - ma);
      eg += __shfl_xor(eg, 16);
      ea += __shfl_xor(ea, 16);
      if (wv < 2 && lhi == 0)
        loss_acc += (mg + __logf(eg)) - (ma + __logf(ea));
    }
  }

  // block reduction of loss
  loss_acc += __shfl_xor(loss_acc, 1);
  loss_acc += __shfl_xor(loss_acc, 2);
  loss_acc += __shfl_xor(loss_acc, 4);
  loss_acc += __shfl_xor(loss_acc, 8);
  loss_acc += __shfl_xor(loss_acc, 16);
  loss_acc += __shfl_xor(loss_acc, 32);
  if (lane == 0) red_s[wv] = loss_acc;
  __syncthreads();
  if (tid == 0) {
    float s = 0.f;
    #pragma unroll
    for (int w = 0; w < 8; ++w) s += red_s[w];
    if (partials) partials[blockIdx.x] = s;
    else atomicAdd(out_atomic, s);
  }
}

__global__ void mdn_reg(const float* __restrict__ Wm, const float* __restrict__ Wv,
                        const float* __restrict__ Wg, float* __restrict__ partials,
                        float* __restrict__ out_atomic)
{
  __shared__ float red[4];
  const int gid = blockIdx.x * 256 + threadIdx.x;
  const int stride = 64 * 256;
  float s = 0.f;
  for (int i = gid; i < DX * MDIM * KEXP; i += stride) { float w = Wm[i]; s += w * w; }
  for (int i = gid; i < DX * MDIM * KEXP; i += stride) { float w = Wv[i]; s += w * w; }
  for (int i = gid; i < DT * KEXP; i += stride)        { float w = Wg[i]; s += w * w; }
  s += __shfl_xor(s, 1);
  s += __shfl_xor(s, 2);
  s += __shfl_xor(s, 4);
  s += __shfl_xor(s, 8);
  s += __shfl_xor(s, 16);
  s += __shfl_xor(s, 32);
  if ((threadIdx.x & 63) == 0) red[threadIdx.x >> 6] = s;
  __syncthreads();
  if (threadIdx.x == 0) {
    float b = red[0] + red[1] + red[2] + red[3];
    if (partials) partials[GRID_MAIN + blockIdx.x] = b;
    else atomicAdd(out_atomic, b);
  }
}

__global__ void mdn_final(const float* __restrict__ partials, float* __restrict__ out)
{
  __shared__ float red[4];
  float s = 0.f;
  for (int i = threadIdx.x; i < GRID_MAIN + 64; i += 256) s += partials[i];
  s += __shfl_xor(s, 1);
  s += __shfl_xor(s, 2);
  s += __shfl_xor(s, 4);
  s += __shfl_xor(s, 8);
  s += __shfl_xor(s, 16);
  s += __shfl_xor(s, 32);
  if ((threadIdx.x & 63) == 0) red[threadIdx.x >> 6] = s;
  __syncthreads();
  if (threadIdx.x == 0) out[0] = red[0] + red[1] + red[2] + red[3];
}

extern "C" void kernel_launch(void* const* d_in, const int* in_sizes, int n_in,
                              void* d_out, int out_size, void* d_ws, size_t ws_size,
                              hipStream_t stream)
{
  const float* x  = (const float*)d_in[0];
  const float* t  = (const float*)d_in[1];
  const float* y  = (const float*)d_in[2];
  const float* Wm = (const float*)d_in[3];
  const float* bm = (const float*)d_in[4];
  const float* Wv = (const float*)d_in[5];
  const float* bv = (const float*)d_in[6];
  const float* Wg = (const float*)d_in[7];
  const float* bg = (const float*)d_in[8];
  float* out = (float*)d_out;

  if (ws_size >= (GRID_MAIN + 64) * sizeof(float)) {
    float* partials = (float*)d_ws;
    mdn_main<<<GRID_MAIN, THREADS, 0, stream>>>(x, t, y, Wm, bm, Wv, bv, Wg, bg,
                                                partials, nullptr);
    mdn_reg<<<64, 256, 0, stream>>>(Wm, Wv, Wg, partials, nullptr);
    mdn_final<<<1, 256, 0, stream>>>(partials, out);
  } else {
    hipMemsetAsync(out, 0, sizeof(float), stream);
    mdn_main<<<GRID_MAIN, THREADS, 0, stream>>>(x, t, y, Wm, bm, Wv, bv, Wg, bg,
                                                nullptr, out);
    mdn_reg<<<64, 256, 0, stream>>>(Wm, Wv, Wg, nullptr, out);
  }
}

// Round 10
// 150.719 us; speedup vs baseline: 2.6951x; 2.6951x over previous
//
#include <hip/hip_runtime.h>
#include <hip/hip_bf16.h>

// MDN NLL, fully fused. N=524288 Dx=128 Dt=64 M=32 K=8.
// Memory-bound target: 470 MB reads -> ~75us floor at 6.3 TB/s.
// R10 design: COLUMN-SPLIT waves. 16 waves/block (1024 thr), wave =
// (expert k = wv&7, col-half h = wv>>3). bfrag = 32 regs (was 64) -> true
// demand ~105 <= 128 -> launch_bounds(1024,4): no spill AND 4 waves/SIMD.
// LL splits over m-halves: each wave writes scalar llp[r][h][k]; LSE reader
// adds both halves (no extra barrier). x,t staged bf16 in LDS (reg-staged,
// cvt at stage; zero cvt in MFMA phase); y staged f32. Dedicated stager
// groups: x=tid<512, t=512..767, y=768..1023, loads issued 1 iter early.
// Involution swizzle on all buffers; 2 lgkm-only barriers/iter; no vmcnt.
// R2/R5/R6/R9 lesson: bfrag=64 + working ~75 > 128 -> spill at (.,4);
// (.,2) = 2 waves/SIMD latency wall. Shrinking bfrag is the only exit.

#define NN 524288
#define DX 128
#define DT 64
#define MDIM 32
#define KEXP 8
#define TILE_R 32
#define THREADS 1024
#define GRID_MAIN 512
#define TILES_TOTAL (NN / TILE_R)        // 16384
#define TPB (TILES_TOTAL / GRID_MAIN)    // 32

typedef __bf16 bf16x8 __attribute__((ext_vector_type(8)));
typedef float f32x4 __attribute__((ext_vector_type(4)));

__device__ __forceinline__ bf16x8 cvt8(const f32x4 a, const f32x4 b) {
  bf16x8 r;
  r[0] = (__bf16)a[0]; r[1] = (__bf16)a[1]; r[2] = (__bf16)a[2]; r[3] = (__bf16)a[3];
  r[4] = (__bf16)b[0]; r[5] = (__bf16)b[1]; r[6] = (__bf16)b[2]; r[7] = (__bf16)b[3];
  return r;
}

#define MFMA16(a, b, c) __builtin_amdgcn_mfma_f32_16x16x32_bf16(a, b, c, 0, 0, 0)

// LDS-only barrier: global loads stay in flight across it (rule 18 fence).
#define B_LDS() do { \
  asm volatile("s_waitcnt lgkmcnt(0)" ::: "memory"); \
  __builtin_amdgcn_s_barrier(); \
  __builtin_amdgcn_sched_barrier(0); } while (0)

__global__ __launch_bounds__(THREADS, 4) void mdn_main(
    const float* __restrict__ x, const float* __restrict__ t,
    const float* __restrict__ y, const float* __restrict__ Wm,
    const float* __restrict__ bm, const float* __restrict__ Wv,
    const float* __restrict__ bv, const float* __restrict__ Wg,
    const float* __restrict__ bg, float* __restrict__ partials,
    float* __restrict__ out_atomic)
{
  __shared__ __align__(16) unsigned short xs_l[2][TILE_R * DX];   // bf16 2x8KB
  __shared__ __align__(16) unsigned short ts_l[2][TILE_R * DT];   // bf16 2x4KB
  __shared__ __align__(16) float ys_l[2][TILE_R * MDIM];          // f32 2x4KB
  __shared__ __align__(16) unsigned short wg_lds[2 * 64 * 8];     // 2KB
  __shared__ float llp[TILE_R * 20];                              // 2.5KB
  __shared__ float red_s[16];

  const int tid = threadIdx.x;
  const int lane = tid & 63;
  const int wv = tid >> 6;        // 0..15
  const int l15 = lane & 15;
  const int lhi = lane >> 4;      // 0..3
  const int kx = wv & 7;          // expert
  const int hh = wv >> 3;         // column half (m-cols hh*16 .. +16)

  // ---- staging role geometry (involution swizzle: slot s holds global
  // chunk g = s ^ (row&7); readers use the same XOR) ----
  int st_ldsoff;                  // byte offset within destination buffer
  const float* st_base;
  int st_stride;                  // floats per tile
  if (tid < 512) {                // x: 32 rows x 16 chunks (16B bf16 out)
    const int r = tid >> 4, s = tid & 15, g = s ^ (r & 7);
    st_base = x + (size_t)r * DX + g * 8;
    st_stride = TILE_R * DX;
    st_ldsoff = r * 256 + s * 16;
  } else if (tid < 768) {         // t: 32 rows x 8 chunks
    const int u = tid - 512, r = u >> 3, s = u & 7, g = s ^ (r & 7);
    st_base = t + (size_t)r * DT + g * 8;
    st_stride = TILE_R * DT;
    st_ldsoff = r * 128 + s * 16;
  } else {                        // y: 32 rows x 8 chunks (f32x4 out)
    const int u = tid - 768, r = u >> 3, s = u & 7, g = s ^ (r & 7);
    st_base = y + (size_t)r * MDIM + g * 4;
    st_stride = TILE_R * MDIM;
    st_ldsoff = r * 128 + s * 16;
  }

  f32x4 sa, sb;
  auto issue = [&](int tile) {
    const float* p = st_base + (size_t)tile * st_stride;
    sa = *(const f32x4*)p;
    if (tid < 768) sb = *(const f32x4*)(p + 4);
  };
  auto commit = [&](int buf) {
    if (tid < 512)      *(bf16x8*)((char*)xs_l[buf] + st_ldsoff) = cvt8(sa, sb);
    else if (tid < 768) *(bf16x8*)((char*)ts_l[buf] + st_ldsoff) = cvt8(sa, sb);
    else                *(f32x4*)((char*)ys_l[buf] + st_ldsoff) = sa;
  };

  const int first = blockIdx.x * TPB;
  issue(first);    // tile-0 loads in flight under the weight prologue

  // biases once, direct from global: lane's 4 m's = hh*16 + lhi*4 + j
  const f32x4 bmean = *(const f32x4*)&bm[kx * MDIM + hh * 16 + lhi * 4];
  const f32x4 blv   = *(const f32x4*)&bv[kx * MDIM + hh * 16 + lhi * 4];
  f32x4 bgv = {0.f, 0.f, 0.f, 0.f};
  if (wv < 4) bgv = *(const f32x4*)&bg[(lhi & 1) * 4];

  // W fragments (A-operand, transposed MFMA): ct 0 = mean, 1 = logvar;
  // cols = hh*16 + l15; k = lhi*8 + i.  8 frags = 32 regs.
  bf16x8 bfrag[2][4];
  #pragma unroll
  for (int ct = 0; ct < 2; ++ct) {
    const float* W = (ct ? Wv : Wm) + (size_t)kx * (DX * MDIM);
    const int mcol = hh * 16 + l15;
    #pragma unroll
    for (int kk = 0; kk < 4; ++kk) {
      bf16x8 tmp;
      #pragma unroll
      for (int i = 0; i < 8; ++i)
        tmp[i] = (__bf16)W[(kk * 32 + lhi * 8 + i) * MDIM + mcol];
      bfrag[ct][kk] = tmp;
    }
  }
  // Gate weights -> LDS (one wave; rows >= KEXP zero-padded)
  if (wv == 4) {
    #pragma unroll
    for (int kk = 0; kk < 2; ++kk) {
      bf16x8 tmp;
      #pragma unroll
      for (int i = 0; i < 8; ++i) {
        const int d = kk * 32 + lhi * 8 + i;
        tmp[i] = (__bf16)((l15 < KEXP) ? Wg[d * KEXP + l15] : 0.f);
      }
      *(bf16x8*)((char*)wg_lds + (kk * 64 + lane) * 16) = tmp;
    }
  }

  commit(0);
  B_LDS();        // tile 0 + wg visible

  const int grt = wv & 1;          // gate sample-half (waves 0..3)
  float loss_acc = 0.f;
  const float HL2PI = 0.91893853320467274f;   // 0.5*log(2*pi)

  for (int it = 0; it < TPB; ++it) {
    const int cur = it & 1;
    issue(first + ((it + 1 < TPB) ? it + 1 : it));   // next tile, early

    // ---- region A: expert MFMAs + half-column Gaussian-LL ----
    const unsigned short* xc = xs_l[cur];
    const float* yc = ys_l[cur];
    #pragma unroll
    for (int rt = 0; rt < 2; ++rt) {
      const int rr = rt * 16 + l15;     // sample (B-col = l15)
      const int r7 = rr & 7;
      f32x4 acc0 = bmean, acc1 = blv;
      #pragma unroll
      for (int kk = 0; kk < 4; ++kk) {
        const int s = (kk * 4 + lhi) ^ r7;
        const bf16x8 af = *(const bf16x8*)((const char*)xc + rr * 256 + s * 16);
        acc0 = MFMA16(bfrag[0][kk], af, acc0);
        acc1 = MFMA16(bfrag[1][kk], af, acc1);
      }
      // D: col = l15 = sample, row = lhi*4+j = m (within half hh)
      const int sy = (hh * 4 + lhi) ^ r7;
      const f32x4 y4 = *(const f32x4*)&yc[rr * 32 + sy * 4];
      float part = 0.f;
      #pragma unroll
      for (int j = 0; j < 4; ++j) {
        const float d = y4[j] - acc0[j];
        part += d * d * (0.5f * __expf(-acc1[j])) + 0.5f * acc1[j];
      }
      part += __shfl_xor(part, 16);
      part += __shfl_xor(part, 32);
      if (lhi == 0) llp[rr * 20 + hh * 8 + kx] = -(part + 16.0f * HL2PI);
    }
    B_LDS();    // #1: llp visible; xs/ys reads of [cur] done

    // ---- region B: gate + LSE (waves 0-3) and restage (all roles) ----
    if (wv < 4) {
      const int rr = grt * 16 + l15;
      const int r7 = rr & 7;
      f32x4 g = {0.f, 0.f, 0.f, 0.f};
      #pragma unroll
      for (int kk = 0; kk < 2; ++kk) {
        const int s = (kk * 4 + lhi) ^ r7;
        const bf16x8 tf = *(const bf16x8*)((const char*)ts_l[cur] + rr * 128 + s * 16);
        const bf16x8 wf = *(const bf16x8*)((const char*)wg_lds + (kk * 64 + lane) * 16);
        g = MFMA16(wf, tf, g);
      }
      // D[k][r]: row = lhi*4+j = expert (lhi<2 valid), col = l15 = sample
      f32x4 lgv, a4;
      const f32x4 lvA = *(const f32x4*)&llp[rr * 20 + (lhi & 1) * 4];
      const f32x4 lvB = *(const f32x4*)&llp[rr * 20 + 8 + (lhi & 1) * 4];
      #pragma unroll
      for (int j = 0; j < 4; ++j) {
        lgv[j] = g[j] + bgv[j];
        a4[j] = lgv[j] + lvA[j] + lvB[j];
      }
      float mg = fmaxf(fmaxf(lgv[0], lgv[1]), fmaxf(lgv[2], lgv[3]));
      float ma = fmaxf(fmaxf(a4[0], a4[1]), fmaxf(a4[2], a4[3]));
      mg = fmaxf(mg, __shfl_xor(mg, 16));
      ma = fmaxf(ma, __shfl_xor(ma, 16));
      float eg = __expf(lgv[0] - mg) + __expf(lgv[1] - mg)
               + __expf(lgv[2] - mg) + __expf(lgv[3] - mg);
      float ea = __expf(a4[0] - ma) + __expf(a4[1] - ma)
               + __expf(a4[2] - ma) + __expf(a4[3] - ma);
      eg += __shfl_xor(eg, 16);
      ea += __shfl_xor(ea, 16);
      if (wv < 2 && lhi == 0)
        loss_acc += (mg + __logf(eg)) - (ma + __logf(ea));
    }
    commit(cur ^ 1);   // write next tile into the other buffers
    B_LDS();    // #2: staged buffers visible for next iter
  }

  // block reduction of loss
  loss_acc += __shfl_xor(loss_acc, 1);
  loss_acc += __shfl_xor(loss_acc, 2);
  loss_acc += __shfl_xor(loss_acc, 4);
  loss_acc += __shfl_xor(loss_acc, 8);
  loss_acc += __shfl_xor(loss_acc, 16);
  loss_acc += __shfl_xor(loss_acc, 32);
  if (lane == 0) red_s[wv] = loss_acc;
  __syncthreads();
  if (tid == 0) {
    float s = 0.f;
    #pragma unroll
    for (int w = 0; w < 16; ++w) s += red_s[w];
    if (partials) partials[blockIdx.x] = s;
    else atomicAdd(out_atomic, s);
  }
}

__global__ void mdn_reg(const float* __restrict__ Wm, const float* __restrict__ Wv,
                        const float* __restrict__ Wg, float* __restrict__ partials,
                        float* __restrict__ out_atomic)
{
  __shared__ float red[4];
  const int gid = blockIdx.x * 256 + threadIdx.x;
  const int stride = 64 * 256;
  float s = 0.f;
  for (int i = gid; i < DX * MDIM * KEXP; i += stride) { float w = Wm[i]; s += w * w; }
  for (int i = gid; i < DX * MDIM * KEXP; i += stride) { float w = Wv[i]; s += w * w; }
  for (int i = gid; i < DT * KEXP; i += stride)        { float w = Wg[i]; s += w * w; }
  s += __shfl_xor(s, 1);
  s += __shfl_xor(s, 2);
  s += __shfl_xor(s, 4);
  s += __shfl_xor(s, 8);
  s += __shfl_xor(s, 16);
  s += __shfl_xor(s, 32);
  if ((threadIdx.x & 63) == 0) red[threadIdx.x >> 6] = s;
  __syncthreads();
  if (threadIdx.x == 0) {
    float b = red[0] + red[1] + red[2] + red[3];
    if (partials) partials[GRID_MAIN + blockIdx.x] = b;
    else atomicAdd(out_atomic, b);
  }
}

__global__ void mdn_final(const float* __restrict__ partials, float* __restrict__ out)
{
  __shared__ float red[4];
  float s = 0.f;
  for (int i = threadIdx.x; i < GRID_MAIN + 64; i += 256) s += partials[i];
  s += __shfl_xor(s, 1);
  s += __shfl_xor(s, 2);
  s += __shfl_xor(s, 4);
  s += __shfl_xor(s, 8);
  s += __shfl_xor(s, 16);
  s += __shfl_xor(s, 32);
  if ((threadIdx.x & 63) == 0) red[threadIdx.x >> 6] = s;
  __syncthreads();
  if (threadIdx.x == 0) out[0] = red[0] + red[1] + red[2] + red[3];
}

extern "C" void kernel_launch(void* const* d_in, const int* in_sizes, int n_in,
                              void* d_out, int out_size, void* d_ws, size_t ws_size,
                              hipStream_t stream)
{
  const float* x  = (const float*)d_in[0];
  const float* t  = (const float*)d_in[1];
  const float* y  = (const float*)d_in[2];
  const float* Wm = (const float*)d_in[3];
  const float* bm = (const float*)d_in[4];
  const float* Wv = (const float*)d_in[5];
  const float* bv = (const float*)d_in[6];
  const float* Wg = (const float*)d_in[7];
  const float* bg = (const float*)d_in[8];
  float* out = (float*)d_out;

  if (ws_size >= (GRID_MAIN + 64) * sizeof(float)) {
    float* partials = (float*)d_ws;
    mdn_main<<<GRID_MAIN, THREADS, 0, stream>>>(x, t, y, Wm, bm, Wv, bv, Wg, bg,
                                                partials, nullptr);
    mdn_reg<<<64, 256, 0, stream>>>(Wm, Wv, Wg, partials, nullptr);
    mdn_final<<<1, 256, 0, stream>>>(partials, out);
  } else {
    hipMemsetAsync(out, 0, sizeof(float), stream);
    mdn_main<<<GRID_MAIN, THREADS, 0, stream>>>(x, t, y, Wm, bm, Wv, bv, Wg, bg,
                                                nullptr, out);
    mdn_reg<<<64, 256, 0, stream>>>(Wm, Wv, Wg, nullptr, out);
  }
}